// Round 1
// baseline (194.497 us; speedup 1.0000x reference)
//
#include <hip/hip_runtime.h>
#include <hip/hip_bf16.h>

#define N 192
#define CZ 128
#define NH 4
#define CH 32
#define WIN 16
#define NROWS (N*N)   // 36864

// ---------------- K1: LayerNorm + Q/K/V/Gate/TB projections ----------------
__global__ __launch_bounds__(256) void k_proj(
    const float* __restrict__ z, const float* __restrict__ lnw, const float* __restrict__ lnb,
    const float* __restrict__ wq, const float* __restrict__ wk, const float* __restrict__ wv,
    const float* __restrict__ wg, const float* __restrict__ bg, const float* __restrict__ wbias,
    float* __restrict__ q, float* __restrict__ k, float* __restrict__ v,
    float* __restrict__ g, float* __restrict__ tb)
{
    __shared__ float zl[16][CZ];
    const int row0 = blockIdx.x * 16;
    const int tid = threadIdx.x;
    const int wave = tid >> 6, lane = tid & 63;
    {
        // wave handles 4 rows; 16 lanes per row; each lane 8 channels
        const int r  = wave*4 + (lane >> 4);
        const int li = lane & 15;
        const float* zr = z + (size_t)(row0 + r)*CZ + li*8;
        float4 a = ((const float4*)zr)[0];
        float4 b = ((const float4*)zr)[1];
        float s  = a.x+a.y+a.z+a.w + b.x+b.y+b.z+b.w;
        float s2 = a.x*a.x+a.y*a.y+a.z*a.z+a.w*a.w + b.x*b.x+b.y*b.y+b.z*b.z+b.w*b.w;
        #pragma unroll
        for (int off=1; off<16; off<<=1) { s += __shfl_xor(s, off); s2 += __shfl_xor(s2, off); }
        const float mu   = s * (1.f/CZ);
        const float rstd = rsqrtf(s2*(1.f/CZ) - mu*mu + 1e-5f);
        const int c0 = li*8;
        float vals[8] = {a.x,a.y,a.z,a.w,b.x,b.y,b.z,b.w};
        #pragma unroll
        for (int t=0; t<8; t++)
            zl[r][c0+t] = (vals[t]-mu)*rstd*lnw[c0+t] + lnb[c0+t];
    }
    __syncthreads();

    const int col   = tid & 127;
    const int rhalf = tid >> 7;  // 0 or 1
    float acc[8][4];
    #pragma unroll
    for (int ri=0; ri<8; ri++)
        #pragma unroll
        for (int m=0; m<4; m++) acc[ri][m] = 0.f;

    #pragma unroll 8
    for (int kk=0; kk<CZ; kk++) {
        const float a0 = wq[kk*128+col];
        const float a1 = wk[kk*128+col];
        const float a2 = wv[kk*128+col];
        const float a3 = wg[kk*128+col];
        #pragma unroll
        for (int ri=0; ri<8; ri++) {
            const float zv = zl[rhalf + 2*ri][kk];   // LDS broadcast within wave
            acc[ri][0] += zv*a0; acc[ri][1] += zv*a1;
            acc[ri][2] += zv*a2; acc[ri][3] += zv*a3;
        }
    }
    const float bgv = bg[col];
    #pragma unroll
    for (int ri=0; ri<8; ri++) {
        const size_t o = (size_t)(row0 + rhalf + 2*ri)*128 + col;
        q[o] = acc[ri][0];
        k[o] = acc[ri][1];
        v[o] = acc[ri][2];
        g[o] = 1.f/(1.f + __expf(-(acc[ri][3] + bgv)));
    }
    // triangle bias projection: 64 threads, one (row, head) each
    if (tid < 64) {
        const int r = tid >> 2, h = tid & 3;
        float s = 0.f;
        for (int kk=0; kk<CZ; kk++) s += zl[r][kk]*wbias[kk*4 + h];
        tb[(size_t)(row0 + r)*4 + h] = s;
    }
}

// ---------------- K2: windowed attention + gate (og aliases q) ----------------
__global__ __launch_bounds__(128) void k_attn(
    const float* __restrict__ q, const float* __restrict__ k, const float* __restrict__ v,
    const float* __restrict__ g, const float* __restrict__ tb, const float* __restrict__ mask,
    float* __restrict__ og)
{
    // [jj][h][c] with stride 33 in c: bank = (4*jj + h + c) % 32 -> 2 lanes/bank (free)
    __shared__ float kl[47][NH][33];
    __shared__ float vl[47][NH][33];
    const int i   = blockIdx.y;
    const int j0  = blockIdx.x * 32;
    const int tid = threadIdx.x;

    for (int idx = tid; idx < 47*128; idx += 128) {
        const int row = idx >> 7, c = idx & 127;
        const int jj  = j0 - 8 + row;
        const int jjc = min(max(jj, 0), N-1);
        const size_t goff = ((size_t)i*N + jjc)*CZ + c;
        kl[row][c>>5][c&31] = k[goff];
        vl[row][c>>5][c&31] = v[goff];
    }
    __syncthreads();

    const int jloc = tid >> 2, h = tid & 3;
    const int j = j0 + jloc;
    const size_t base = ((size_t)i*N + j)*CZ + h*CH;

    float qv[CH];
    #pragma unroll
    for (int c4=0; c4<CH/4; c4++) {
        float4 t = ((const float4*)(q+base))[c4];
        qv[c4*4]=t.x; qv[c4*4+1]=t.y; qv[c4*4+2]=t.z; qv[c4*4+3]=t.w;
    }

    const float scale = 0.17677669529663688f; // 1/sqrt(32)
    float lg[WIN];
    #pragma unroll
    for (int w=0; w<WIN; w++) {
        const int jj  = j - 8 + w;
        const int rel = jloc + w;               // in [0,46]
        const int jjc = min(max(jj, 0), N-1);
        float dot = 0.f;
        #pragma unroll
        for (int c=0; c<CH; c++) dot += qv[c]*kl[rel][h][c];
        const bool ok = (jj >= 0) && (jj < N) && (mask[(size_t)i*N + jjc] > 0.f);
        lg[w] = dot*scale + tb[((size_t)j*N + jjc)*4 + h] + (ok ? 0.f : -1e9f);
    }
    float mx = lg[0];
    #pragma unroll
    for (int w=1; w<WIN; w++) mx = fmaxf(mx, lg[w]);
    float sum = 0.f;
    #pragma unroll
    for (int w=0; w<WIN; w++) { lg[w] = __expf(lg[w]-mx); sum += lg[w]; }
    const float inv = 1.f/sum;

    float o[CH];
    #pragma unroll
    for (int c=0; c<CH; c++) o[c] = 0.f;
    #pragma unroll
    for (int w=0; w<WIN; w++) {
        const float p   = lg[w]*inv;
        const int   rel = jloc + w;
        #pragma unroll
        for (int c=0; c<CH; c++) o[c] += p*vl[rel][h][c];
    }

    #pragma unroll
    for (int c4=0; c4<CH/4; c4++) {
        float4 gt = ((const float4*)(g+base))[c4];
        float4 ot;
        ot.x = o[c4*4+0]*gt.x; ot.y = o[c4*4+1]*gt.y;
        ot.z = o[c4*4+2]*gt.z; ot.w = o[c4*4+3]*gt.w;
        ((float4*)(og+base))[c4] = ot;   // og aliases q: each element read-then-written by this thread only
    }
}

// ---------------- K3: out = og @ w_out + b_out ----------------
__global__ __launch_bounds__(256) void k_out(
    const float* __restrict__ og, const float* __restrict__ wout, const float* __restrict__ bout,
    float* __restrict__ out)
{
    __shared__ float ol[16][CZ];
    const int row0 = blockIdx.x * 16;
    const int tid = threadIdx.x;
    for (int idx = tid; idx < 16*CZ; idx += 256)
        ol[idx>>7][idx&127] = og[(size_t)row0*CZ + idx];
    __syncthreads();

    const int col   = tid & 127;
    const int rhalf = tid >> 7;
    float acc[8];
    #pragma unroll
    for (int ri=0; ri<8; ri++) acc[ri] = 0.f;

    #pragma unroll 8
    for (int kk=0; kk<CZ; kk++) {
        const float wv_ = wout[kk*128+col];
        #pragma unroll
        for (int ri=0; ri<8; ri++)
            acc[ri] += ol[rhalf+2*ri][kk]*wv_;
    }
    const float bv = bout[col];
    #pragma unroll
    for (int ri=0; ri<8; ri++)
        out[(size_t)(row0+rhalf+2*ri)*CZ + col] = acc[ri] + bv;
}

extern "C" void kernel_launch(void* const* d_in, const int* in_sizes, int n_in,
                              void* d_out, int out_size, void* d_ws, size_t ws_size,
                              hipStream_t stream)
{
    const float* z    = (const float*)d_in[0];
    const float* mask = (const float*)d_in[1];
    const float* lnw  = (const float*)d_in[2];
    const float* lnb  = (const float*)d_in[3];
    const float* wq   = (const float*)d_in[4];
    const float* wk   = (const float*)d_in[5];
    const float* wv   = (const float*)d_in[6];
    const float* wb   = (const float*)d_in[7];
    const float* wg   = (const float*)d_in[8];
    const float* bg   = (const float*)d_in[9];
    const float* wo   = (const float*)d_in[10];
    const float* bo   = (const float*)d_in[11];
    // d_in[12] = window_size (scalar int, fixed 16 for this problem shape)

    const size_t NE = (size_t)NROWS*CZ;      // 4,718,592 floats per field
    float* q  = (float*)d_ws;
    float* k  = q + NE;
    float* v  = k + NE;
    float* g  = v + NE;
    float* tb = g + NE;                      // NROWS*4 floats
    float* og = q;                           // alias (safe: per-thread read-then-write)
    if (ws_size < (4*NE + (size_t)NROWS*4)*sizeof(float)) return;

    k_proj<<<NROWS/16, 256, 0, stream>>>(z, lnw, lnb, wq, wk, wv, wg, bg, wb, q, k, v, g, tb);
    k_attn<<<dim3(N/32, N), 128, 0, stream>>>(q, k, v, g, tb, mask, og);
    k_out<<<NROWS/16, 256, 0, stream>>>(og, wo, bo, (float*)d_out);
}

// Round 2
// 134.683 us; speedup vs baseline: 1.4441x; 1.4441x over previous
//
#include <hip/hip_runtime.h>
#include <hip/hip_bf16.h>

#define N 192
#define CZ 128
#define NH 4
#define CH 32
#define WIN 16
#define NROWS (N*N)   // 36864

// ---------------- K1: LayerNorm + Q/K/V/Gate/TB projections ----------------
__global__ __launch_bounds__(256) void k_proj(
    const float* __restrict__ z, const float* __restrict__ lnw, const float* __restrict__ lnb,
    const float* __restrict__ wq, const float* __restrict__ wk, const float* __restrict__ wv,
    const float* __restrict__ wg, const float* __restrict__ bg, const float* __restrict__ wbias,
    float* __restrict__ q, float* __restrict__ k, float* __restrict__ v,
    float* __restrict__ g, float* __restrict__ tb)
{
    __shared__ float zl[16][CZ];
    const int row0 = blockIdx.x * 16;
    const int tid = threadIdx.x;
    const int wave = tid >> 6, lane = tid & 63;
    {
        const int r  = wave*4 + (lane >> 4);
        const int li = lane & 15;
        const float* zr = z + (size_t)(row0 + r)*CZ + li*8;
        float4 a = ((const float4*)zr)[0];
        float4 b = ((const float4*)zr)[1];
        float s  = a.x+a.y+a.z+a.w + b.x+b.y+b.z+b.w;
        float s2 = a.x*a.x+a.y*a.y+a.z*a.z+a.w*a.w + b.x*b.x+b.y*b.y+b.z*b.z+b.w*b.w;
        #pragma unroll
        for (int off=1; off<16; off<<=1) { s += __shfl_xor(s, off); s2 += __shfl_xor(s2, off); }
        const float mu   = s * (1.f/CZ);
        const float rstd = rsqrtf(s2*(1.f/CZ) - mu*mu + 1e-5f);
        const int c0 = li*8;
        float vals[8] = {a.x,a.y,a.z,a.w,b.x,b.y,b.z,b.w};
        #pragma unroll
        for (int t=0; t<8; t++)
            zl[r][c0+t] = (vals[t]-mu)*rstd*lnw[c0+t] + lnb[c0+t];
    }
    __syncthreads();

    const int col   = tid & 127;
    const int rhalf = tid >> 7;  // 0 or 1
    float acc[8][4];
    #pragma unroll
    for (int ri=0; ri<8; ri++)
        #pragma unroll
        for (int m=0; m<4; m++) acc[ri][m] = 0.f;

    #pragma unroll 8
    for (int kk=0; kk<CZ; kk++) {
        const float a0 = wq[kk*128+col];
        const float a1 = wk[kk*128+col];
        const float a2 = wv[kk*128+col];
        const float a3 = wg[kk*128+col];
        #pragma unroll
        for (int ri=0; ri<8; ri++) {
            const float zv = zl[rhalf + 2*ri][kk];
            acc[ri][0] += zv*a0; acc[ri][1] += zv*a1;
            acc[ri][2] += zv*a2; acc[ri][3] += zv*a3;
        }
    }
    const float bgv = bg[col];
    #pragma unroll
    for (int ri=0; ri<8; ri++) {
        const size_t o = (size_t)(row0 + rhalf + 2*ri)*128 + col;
        q[o] = acc[ri][0];
        k[o] = acc[ri][1];
        v[o] = acc[ri][2];
        g[o] = 1.f/(1.f + __expf(-(acc[ri][3] + bgv)));
    }
    if (tid < 64) {
        const int r = tid >> 2, h = tid & 3;
        float s = 0.f;
        for (int kk=0; kk<CZ; kk++) s += zl[r][kk]*wbias[kk*4 + h];
        tb[(size_t)(row0 + r)*4 + h] = s;
    }
}

// ---------------- K2: windowed attention + gate (og aliases q) ----------------
// 256 threads: tid = jloc*8 + h*2 + chalf.  Each thread owns 16 channels.
__global__ __launch_bounds__(256, 3) void k_attn(
    const float* __restrict__ q, const float* __restrict__ k, const float* __restrict__ v,
    const float* __restrict__ g, const float* __restrict__ tb, const float* __restrict__ mask,
    float* __restrict__ og)
{
    // [jj][h][33]: b128 start bank = (4*rel + h + 16*chalf + 4*c4) % 32 ->
    // 64 lanes hit each start value exactly twice -> even 4 words/bank (b128 floor)
    __shared__ float kl[47][NH][33];
    __shared__ float vl[47][NH][33];
    __shared__ float ml[47];
    const int i   = blockIdx.y;
    const int j0  = blockIdx.x * 32;
    const int tid = threadIdx.x;

    // stage K/V window with float4 loads/stores
    for (int idx = tid; idx < 47*32; idx += 256) {
        const int row = idx >> 5;          // 0..46
        const int c4  = idx & 31;          // float4 index in 128 channels
        const int jj  = j0 - 8 + row;
        const int jjc = min(max(jj, 0), N-1);
        const size_t goff = ((size_t)i*N + jjc)*CZ + c4*4;
        float4 kk4 = *(const float4*)(k + goff);
        float4 vv4 = *(const float4*)(v + goff);
        const int hh = c4 >> 3;
        const int co = (c4 & 7) * 4;
        *(float4*)&kl[row][hh][co] = kk4;
        *(float4*)&vl[row][hh][co] = vv4;
    }
    if (tid < 47) {
        const int jj  = j0 - 8 + tid;
        const int jjc = min(max(jj, 0), N-1);
        const bool ok = (jj >= 0) && (jj < N) && (mask[(size_t)i*N + jjc] > 0.f);
        ml[tid] = ok ? 0.f : -1e9f;
    }
    __syncthreads();

    const int chalf = tid & 1;
    const int h     = (tid >> 1) & 3;
    const int jloc  = tid >> 3;            // 0..31
    const int j     = j0 + jloc;
    const int c0    = chalf * 16;
    const size_t base = ((size_t)i*N + j)*CZ + h*CH + c0;

    float qv[16];
    #pragma unroll
    for (int c4=0; c4<4; c4++) {
        float4 t = ((const float4*)(q+base))[c4];
        qv[c4*4]=t.x; qv[c4*4+1]=t.y; qv[c4*4+2]=t.z; qv[c4*4+3]=t.w;
    }

    const float scale = 0.17677669529663688f; // 1/sqrt(32)
    float lg[WIN];
    #pragma unroll
    for (int w=0; w<WIN; w++) {
        const int rel = jloc + w;
        float dot = 0.f;
        #pragma unroll
        for (int c4=0; c4<4; c4++) {
            float4 kv = *(const float4*)&kl[rel][h][c0 + c4*4];
            dot += qv[c4*4+0]*kv.x + qv[c4*4+1]*kv.y + qv[c4*4+2]*kv.z + qv[c4*4+3]*kv.w;
        }
        dot += __shfl_xor(dot, 1);          // combine the two c-halves
        const int jj  = j - 8 + w;
        const int jjc = min(max(jj, 0), N-1);
        lg[w] = dot*scale + tb[((size_t)j*N + jjc)*4 + h] + ml[rel];
    }
    float mx = lg[0];
    #pragma unroll
    for (int w=1; w<WIN; w++) mx = fmaxf(mx, lg[w]);
    float sum = 0.f;
    #pragma unroll
    for (int w=0; w<WIN; w++) { lg[w] = __expf(lg[w]-mx); sum += lg[w]; }
    const float inv = 1.f/sum;

    float o[16];
    #pragma unroll
    for (int c=0; c<16; c++) o[c] = 0.f;
    #pragma unroll
    for (int w=0; w<WIN; w++) {
        const float p   = lg[w]*inv;
        const int   rel = jloc + w;
        #pragma unroll
        for (int c4=0; c4<4; c4++) {
            float4 vv = *(const float4*)&vl[rel][h][c0 + c4*4];
            o[c4*4+0] += p*vv.x; o[c4*4+1] += p*vv.y;
            o[c4*4+2] += p*vv.z; o[c4*4+3] += p*vv.w;
        }
    }

    #pragma unroll
    for (int c4=0; c4<4; c4++) {
        float4 gt = ((const float4*)(g+base))[c4];
        float4 ot;
        ot.x = o[c4*4+0]*gt.x; ot.y = o[c4*4+1]*gt.y;
        ot.z = o[c4*4+2]*gt.z; ot.w = o[c4*4+3]*gt.w;
        ((float4*)(og+base))[c4] = ot;   // og aliases q: element read earlier by this same thread only
    }
}

// ---------------- K3: out = og @ w_out + b_out ----------------
__global__ __launch_bounds__(256) void k_out(
    const float* __restrict__ og, const float* __restrict__ wout, const float* __restrict__ bout,
    float* __restrict__ out)
{
    __shared__ float ol[16][CZ];
    const int row0 = blockIdx.x * 16;
    const int tid = threadIdx.x;
    for (int idx = tid; idx < 16*CZ; idx += 256)
        ol[idx>>7][idx&127] = og[(size_t)row0*CZ + idx];
    __syncthreads();

    const int col   = tid & 127;
    const int rhalf = tid >> 7;
    float acc[8];
    #pragma unroll
    for (int ri=0; ri<8; ri++) acc[ri] = 0.f;

    #pragma unroll 8
    for (int kk=0; kk<CZ; kk++) {
        const float wv_ = wout[kk*128+col];
        #pragma unroll
        for (int ri=0; ri<8; ri++)
            acc[ri] += ol[rhalf+2*ri][kk]*wv_;
    }
    const float bv = bout[col];
    #pragma unroll
    for (int ri=0; ri<8; ri++)
        out[(size_t)(row0+rhalf+2*ri)*CZ + col] = acc[ri] + bv;
}

extern "C" void kernel_launch(void* const* d_in, const int* in_sizes, int n_in,
                              void* d_out, int out_size, void* d_ws, size_t ws_size,
                              hipStream_t stream)
{
    const float* z    = (const float*)d_in[0];
    const float* mask = (const float*)d_in[1];
    const float* lnw  = (const float*)d_in[2];
    const float* lnb  = (const float*)d_in[3];
    const float* wq   = (const float*)d_in[4];
    const float* wk   = (const float*)d_in[5];
    const float* wv   = (const float*)d_in[6];
    const float* wb   = (const float*)d_in[7];
    const float* wg   = (const float*)d_in[8];
    const float* bg   = (const float*)d_in[9];
    const float* wo   = (const float*)d_in[10];
    const float* bo   = (const float*)d_in[11];

    const size_t NE = (size_t)NROWS*CZ;
    float* q  = (float*)d_ws;
    float* k  = q + NE;
    float* v  = k + NE;
    float* g  = v + NE;
    float* tb = g + NE;
    float* og = q;                           // alias (safe: per-thread read-then-write)
    if (ws_size < (4*NE + (size_t)NROWS*4)*sizeof(float)) return;

    k_proj<<<NROWS/16, 256, 0, stream>>>(z, lnw, lnb, wq, wk, wv, wg, bg, wb, q, k, v, g, tb);
    k_attn<<<dim3(N/32, N), 256, 0, stream>>>(q, k, v, g, tb, mask, og);
    k_out<<<NROWS/16, 256, 0, stream>>>(og, wo, bo, (float*)d_out);
}

// Round 5
// 94.917 us; speedup vs baseline: 2.0491x; 1.4190x over previous
//
#include <hip/hip_runtime.h>
#include <hip/hip_bf16.h>

#define N 192
#define CZ 128
#define NH 4
#define CH 32
#define WIN 16
#define NROWS (N*N)   // 36864

typedef __attribute__((ext_vector_type(8))) short bf16x8;
typedef __attribute__((ext_vector_type(4))) float f32x4;

static __device__ __forceinline__ ushort f2bf(float x){
    union{float f; unsigned u;} a; a.f = x;
    unsigned r = a.u + 0x7fffu + ((a.u>>16)&1u);   // RNE
    return (ushort)(r>>16);
}
static __device__ __forceinline__ float bf2f(ushort s){
    union{unsigned u; float f;} a; a.u = ((unsigned)s)<<16;
    return a.f;
}

// ---------------- K1: LayerNorm -> zl(bf16) + tb(f32) ----------------
__global__ __launch_bounds__(256) void k_ln(
    const float* __restrict__ z, const float* __restrict__ lnw, const float* __restrict__ lnb,
    const float* __restrict__ wbias, ushort* __restrict__ zl, float* __restrict__ tb)
{
    const int tid = threadIdx.x;
    const int wave = tid >> 6, lane = tid & 63;
    const int r  = wave*4 + (lane >> 4);
    const int li = lane & 15;
    const int row = blockIdx.x*16 + r;
    const float* zr = z + (size_t)row*CZ + li*8;
    float4 a = ((const float4*)zr)[0];
    float4 b = ((const float4*)zr)[1];
    float s  = a.x+a.y+a.z+a.w + b.x+b.y+b.z+b.w;
    float s2 = a.x*a.x+a.y*a.y+a.z*a.z+a.w*a.w + b.x*b.x+b.y*b.y+b.z*b.z+b.w*b.w;
    #pragma unroll
    for (int off=1; off<16; off<<=1) { s += __shfl_xor(s, off); s2 += __shfl_xor(s2, off); }
    const float mu   = s * (1.f/CZ);
    const float rstd = rsqrtf(s2*(1.f/CZ) - mu*mu + 1e-5f);
    const int c0 = li*8;
    float vals[8] = {a.x,a.y,a.z,a.w,b.x,b.y,b.z,b.w};
    float tbp[4] = {0.f,0.f,0.f,0.f};
    uint4 pk; ushort* ph = (ushort*)&pk;
    #pragma unroll
    for (int t=0; t<8; t++) {
        const float nv = (vals[t]-mu)*rstd*lnw[c0+t] + lnb[c0+t];
        ph[t] = f2bf(nv);
        float4 wb4 = *(const float4*)(wbias + (c0+t)*4);
        tbp[0] += nv*wb4.x; tbp[1] += nv*wb4.y;
        tbp[2] += nv*wb4.z; tbp[3] += nv*wb4.w;
    }
    *(uint4*)(zl + (size_t)row*CZ + c0) = pk;
    #pragma unroll
    for (int off=1; off<16; off<<=1) {
        #pragma unroll
        for (int h=0; h<4; h++) tbp[h] += __shfl_xor(tbp[h], off);
    }
    if (li == 0) *(float4*)(tb + (size_t)row*4) = make_float4(tbp[0],tbp[1],tbp[2],tbp[3]);
}

// ---------------- K2: MFMA projections q/k/v/g = zl @ W (+sigmoid for g) ----------------
// grid = 4 matrices x 288 row-blocks; block handles 128 rows (2 tiles x 64), 4 waves x 16 rows.
__global__ __launch_bounds__(256, 4) void k_gemm(
    const ushort* __restrict__ zl,
    const float* __restrict__ wq, const float* __restrict__ wk,
    const float* __restrict__ wv, const float* __restrict__ wg,
    const float* __restrict__ bg,
    ushort* __restrict__ q, ushort* __restrict__ k,
    ushort* __restrict__ v, ushort* __restrict__ g)
{
    __shared__ ushort WT[128][136];    // transposed W, bf16, +16B pad -> even b128 banks
    const int bid  = blockIdx.x;
    const int m    = bid & 3;
    const int rblk = bid >> 2;
    const float* W = (m==0)?wq:(m==1)?wk:(m==2)?wv:wg;
    ushort*      O = (m==0)?q :(m==1)?k :(m==2)?v :g;
    const int tid = threadIdx.x;

    for (int t = tid; t < 4096; t += 256) {
        const int kk = t >> 5;
        const int n0 = (t & 31) * 4;
        float4 w4 = *(const float4*)(W + kk*CZ + n0);
        WT[n0+0][kk] = f2bf(w4.x); WT[n0+1][kk] = f2bf(w4.y);
        WT[n0+2][kk] = f2bf(w4.z); WT[n0+3][kk] = f2bf(w4.w);
    }
    __syncthreads();

    const int wid = tid >> 6, lane = tid & 63;
    const int l16 = lane & 15, lk = lane >> 4;
    #pragma unroll
    for (int it = 0; it < 2; ++it) {
        const int row0 = rblk*128 + it*64 + wid*16;
        bf16x8 af[4];
        #pragma unroll
        for (int ks=0; ks<4; ks++)
            af[ks] = *(const bf16x8*)(zl + (size_t)(row0 + l16)*CZ + ks*32 + lk*8);
        #pragma unroll
        for (int nt=0; nt<8; nt++) {
            f32x4 acc = {0.f,0.f,0.f,0.f};
            #pragma unroll
            for (int ks=0; ks<4; ks++) {
                bf16x8 bf = *(const bf16x8*)(&WT[nt*16 + l16][ks*32 + lk*8]);
                acc = __builtin_amdgcn_mfma_f32_16x16x32_bf16(af[ks], bf, acc, 0, 0, 0);
            }
            const int ocol = nt*16 + l16;
            const int orow = row0 + lk*4;
            if (m == 3) {
                const float bgv = bg[ocol];
                #pragma unroll
                for (int rr=0; rr<4; rr++) {
                    const float val = 1.f/(1.f + __expf(-(acc[rr] + bgv)));
                    O[(size_t)(orow+rr)*CZ + ocol] = f2bf(val);
                }
            } else {
                #pragma unroll
                for (int rr=0; rr<4; rr++)
                    O[(size_t)(orow+rr)*CZ + ocol] = f2bf(acc[rr]);
            }
        }
    }
}

// ---------------- K3: windowed attention + gate (og aliases q), bf16 I/O ----------------
__global__ __launch_bounds__(256, 3) void k_attn(
    const ushort* __restrict__ q, const ushort* __restrict__ k, const ushort* __restrict__ v,
    const ushort* __restrict__ g, const float* __restrict__ tb, const float* __restrict__ mask,
    ushort* __restrict__ og)
{
    __shared__ float kl[47][NH][33];
    __shared__ float vl[47][NH][33];
    __shared__ float ml[47];
    const int i   = blockIdx.y;
    const int j0  = blockIdx.x * 32;
    const int tid = threadIdx.x;

    for (int idx = tid; idx < 47*16; idx += 256) {
        const int row = idx >> 4, c8 = idx & 15;
        const int jj  = j0 - 8 + row;
        const int jjc = min(max(jj, 0), N-1);
        const size_t goff = ((size_t)i*N + jjc)*CZ + c8*8;
        uint4 ku = *(const uint4*)(k + goff);
        uint4 vu = *(const uint4*)(v + goff);
        const int hh = c8 >> 2, co = (c8 & 3)*8;
        const ushort* ks_ = (const ushort*)&ku;
        const ushort* vs_ = (const ushort*)&vu;
        #pragma unroll
        for (int t=0; t<8; t++) {
            kl[row][hh][co+t] = bf2f(ks_[t]);
            vl[row][hh][co+t] = bf2f(vs_[t]);
        }
    }
    if (tid < 47) {
        const int jj  = j0 - 8 + tid;
        const int jjc = min(max(jj, 0), N-1);
        const bool ok = (jj >= 0) && (jj < N) && (mask[(size_t)i*N + jjc] > 0.f);
        ml[tid] = ok ? 0.f : -1e9f;
    }
    __syncthreads();

    const int chalf = tid & 1;
    const int h     = (tid >> 1) & 3;
    const int jloc  = tid >> 3;
    const int j     = j0 + jloc;
    const int c0l   = chalf * 16;
    const size_t base = ((size_t)i*N + j)*CZ + h*CH + c0l;

    float qv[16];
    {
        uint4 q1 = *(const uint4*)(q + base);
        uint4 q2 = *(const uint4*)(q + base + 8);
        const ushort* s1 = (const ushort*)&q1;
        const ushort* s2 = (const ushort*)&q2;
        #pragma unroll
        for (int t=0; t<8; t++) { qv[t] = bf2f(s1[t]); qv[8+t] = bf2f(s2[t]); }
    }

    const float scale = 0.17677669529663688f; // 1/sqrt(32)
    float lg[WIN];
    #pragma unroll
    for (int w=0; w<WIN; w++) {
        const int rel = jloc + w;
        float dot = 0.f;
        #pragma unroll
        for (int c4=0; c4<4; c4++) {
            float4 kv = *(const float4*)&kl[rel][h][c0l + c4*4];
            dot += qv[c4*4+0]*kv.x + qv[c4*4+1]*kv.y + qv[c4*4+2]*kv.z + qv[c4*4+3]*kv.w;
        }
        dot += __shfl_xor(dot, 1);
        const int jj  = j - 8 + w;
        const int jjc = min(max(jj, 0), N-1);
        lg[w] = dot*scale + tb[((size_t)j*N + jjc)*4 + h] + ml[rel];
    }
    float mx = lg[0];
    #pragma unroll
    for (int w=1; w<WIN; w++) mx = fmaxf(mx, lg[w]);
    float sum = 0.f;
    #pragma unroll
    for (int w=0; w<WIN; w++) { lg[w] = __expf(lg[w]-mx); sum += lg[w]; }
    const float inv = 1.f/sum;

    float o[16];
    #pragma unroll
    for (int c=0; c<16; c++) o[c] = 0.f;
    #pragma unroll
    for (int w=0; w<WIN; w++) {
        const float p   = lg[w]*inv;
        const int   rel = jloc + w;
        #pragma unroll
        for (int c4=0; c4<4; c4++) {
            float4 vv = *(const float4*)&vl[rel][h][c0l + c4*4];
            o[c4*4+0] += p*vv.x; o[c4*4+1] += p*vv.y;
            o[c4*4+2] += p*vv.z; o[c4*4+3] += p*vv.w;
        }
    }

    {
        uint4 g1 = *(const uint4*)(g + base);
        uint4 g2 = *(const uint4*)(g + base + 8);
        const ushort* s1 = (const ushort*)&g1;
        const ushort* s2 = (const ushort*)&g2;
        uint4 o1, o2; ushort* p1 = (ushort*)&o1; ushort* p2 = (ushort*)&o2;
        #pragma unroll
        for (int t=0; t<8; t++) {
            p1[t] = f2bf(o[t]   * bf2f(s1[t]));
            p2[t] = f2bf(o[8+t] * bf2f(s2[t]));
        }
        *(uint4*)(og + base)     = o1;   // og aliases q: read earlier by this thread only
        *(uint4*)(og + base + 8) = o2;
    }
}

// ---------------- K4: out = og @ w_out + b_out (MFMA, fp32 out) ----------------
__global__ __launch_bounds__(256, 4) void k_outg(
    const ushort* __restrict__ og, const float* __restrict__ wout,
    const float* __restrict__ bout, float* __restrict__ out)
{
    __shared__ ushort WT[128][136];
    const int tid = threadIdx.x;
    for (int t = tid; t < 4096; t += 256) {
        const int kk = t >> 5;
        const int n0 = (t & 31) * 4;
        float4 w4 = *(const float4*)(wout + kk*CZ + n0);
        WT[n0+0][kk] = f2bf(w4.x); WT[n0+1][kk] = f2bf(w4.y);
        WT[n0+2][kk] = f2bf(w4.z); WT[n0+3][kk] = f2bf(w4.w);
    }
    __syncthreads();

    const int wid = tid >> 6, lane = tid & 63;
    const int l16 = lane & 15, lk = lane >> 4;
    const int row0 = blockIdx.x*64 + wid*16;
    bf16x8 af[4];
    #pragma unroll
    for (int ks=0; ks<4; ks++)
        af[ks] = *(const bf16x8*)(og + (size_t)(row0 + l16)*CZ + ks*32 + lk*8);
    #pragma unroll
    for (int nt=0; nt<8; nt++) {
        f32x4 acc = {0.f,0.f,0.f,0.f};
        #pragma unroll
        for (int ks=0; ks<4; ks++) {
            bf16x8 bf = *(const bf16x8*)(&WT[nt*16 + l16][ks*32 + lk*8]);
            acc = __builtin_amdgcn_mfma_f32_16x16x32_bf16(af[ks], bf, acc, 0, 0, 0);
        }
        const int ocol = nt*16 + l16;
        const int orow = row0 + lk*4;
        const float bv = bout[ocol];
        #pragma unroll
        for (int rr=0; rr<4; rr++)
            out[(size_t)(orow+rr)*CZ + ocol] = acc[rr] + bv;
    }
}

extern "C" void kernel_launch(void* const* d_in, const int* in_sizes, int n_in,
                              void* d_out, int out_size, void* d_ws, size_t ws_size,
                              hipStream_t stream)
{
    const float* z    = (const float*)d_in[0];
    const float* mask = (const float*)d_in[1];
    const float* lnw  = (const float*)d_in[2];
    const float* lnb  = (const float*)d_in[3];
    const float* wq   = (const float*)d_in[4];
    const float* wk   = (const float*)d_in[5];
    const float* wv   = (const float*)d_in[6];
    const float* wb   = (const float*)d_in[7];
    const float* wg   = (const float*)d_in[8];
    const float* bg   = (const float*)d_in[9];
    const float* wo   = (const float*)d_in[10];
    const float* bo   = (const float*)d_in[11];

    const size_t NE = (size_t)NROWS*CZ;
    ushort* zl = (ushort*)d_ws;          // bf16 [NROWS][128]
    ushort* q  = zl + NE;
    ushort* k  = q + NE;
    ushort* v  = k + NE;
    ushort* g  = v + NE;
    float*  tb = (float*)(g + NE);       // f32 [NROWS][4]
    ushort* og = q;                      // alias (safe: per-thread read-then-write)
    if (ws_size < 5*NE*sizeof(ushort) + (size_t)NROWS*4*sizeof(float)) return;

    k_ln  <<<NROWS/16, 256, 0, stream>>>(z, lnw, lnb, wb, zl, tb);
    k_gemm<<<4*(NROWS/128), 256, 0, stream>>>(zl, wq, wk, wv, wg, bg, q, k, v, g);
    k_attn<<<dim3(N/32, N), 256, 0, stream>>>(q, k, v, g, tb, mask, og);
    k_outg<<<NROWS/64, 256, 0, stream>>>(og, wo, bo, (float*)d_out);
}

// Round 8
// 78.255 us; speedup vs baseline: 2.4854x; 1.2129x over previous
//
#include <hip/hip_runtime.h>
#include <hip/hip_bf16.h>

#define N 192
#define CZ 128
#define NH 4
#define CH 32
#define WIN 16
#define NROWS (N*N)   // 36864

typedef __attribute__((ext_vector_type(8))) short bf16x8;
typedef __attribute__((ext_vector_type(4))) float f32x4;

static __device__ __forceinline__ ushort f2bf(float x){
    union{float f; unsigned u;} a; a.f = x;
    unsigned r = a.u + 0x7fffu + ((a.u>>16)&1u);   // RNE
    return (ushort)(r>>16);
}
static __device__ __forceinline__ float bf2f(ushort s){
    union{unsigned u; float f;} a; a.u = ((unsigned)s)<<16;
    return a.f;
}

// ---------------- K1: LayerNorm -> zl(bf16) + tb(f32) ----------------
__global__ __launch_bounds__(256) void k_ln(
    const float* __restrict__ z, const float* __restrict__ lnw, const float* __restrict__ lnb,
    const float* __restrict__ wbias, ushort* __restrict__ zl, float* __restrict__ tb)
{
    const int tid = threadIdx.x;
    const int wave = tid >> 6, lane = tid & 63;
    const int r  = wave*4 + (lane >> 4);
    const int li = lane & 15;
    const int row = blockIdx.x*16 + r;
    const float* zr = z + (size_t)row*CZ + li*8;
    float4 a = ((const float4*)zr)[0];
    float4 b = ((const float4*)zr)[1];
    float s  = a.x+a.y+a.z+a.w + b.x+b.y+b.z+b.w;
    float s2 = a.x*a.x+a.y*a.y+a.z*a.z+a.w*a.w + b.x*b.x+b.y*b.y+b.z*b.z+b.w*b.w;
    #pragma unroll
    for (int off=1; off<16; off<<=1) { s += __shfl_xor(s, off); s2 += __shfl_xor(s2, off); }
    const float mu   = s * (1.f/CZ);
    const float rstd = rsqrtf(s2*(1.f/CZ) - mu*mu + 1e-5f);
    const int c0 = li*8;
    float vals[8] = {a.x,a.y,a.z,a.w,b.x,b.y,b.z,b.w};
    float tbp[4] = {0.f,0.f,0.f,0.f};
    uint4 pk; ushort* ph = (ushort*)&pk;
    #pragma unroll
    for (int t=0; t<8; t++) {
        const float nv = (vals[t]-mu)*rstd*lnw[c0+t] + lnb[c0+t];
        ph[t] = f2bf(nv);
        float4 wb4 = *(const float4*)(wbias + (c0+t)*4);
        tbp[0] += nv*wb4.x; tbp[1] += nv*wb4.y;
        tbp[2] += nv*wb4.z; tbp[3] += nv*wb4.w;
    }
    *(uint4*)(zl + (size_t)row*CZ + c0) = pk;
    #pragma unroll
    for (int off=1; off<16; off<<=1) {
        #pragma unroll
        for (int h=0; h<4; h++) tbp[h] += __shfl_xor(tbp[h], off);
    }
    if (li == 0) *(float4*)(tb + (size_t)row*4) = make_float4(tbp[0],tbp[1],tbp[2],tbp[3]);
}

// ---------------- K2: MFMA projections, B held in registers (no LDS) ----------------
// grid = 4 matrices x 288 row-blocks. Block = 4 waves; wave w owns cols [w*32, w*32+32).
// Each wave loads its 8 B-fragments once from global W (L2-hot), loops 8 row-tiles.
__global__ __launch_bounds__(256, 4) void k_gemm(
    const ushort* __restrict__ zl,
    const float* __restrict__ wq, const float* __restrict__ wk,
    const float* __restrict__ wv, const float* __restrict__ wg,
    const float* __restrict__ bg,
    ushort* __restrict__ q, ushort* __restrict__ k,
    ushort* __restrict__ v, ushort* __restrict__ g)
{
    const int bid  = blockIdx.x;
    const int m    = bid & 3;
    const int rblk = bid >> 2;
    const float* W = (m==0)?wq:(m==1)?wk:(m==2)?wv:wg;
    ushort*      O = (m==0)?q :(m==1)?k :(m==2)?v :g;
    const int tid = threadIdx.x;
    const int wid = tid >> 6, lane = tid & 63;
    const int l16 = lane & 15, lk = lane >> 4;

    // B fragments: bfrag[nt2][ks] lane(l16,lk) holds W[ks*32+lk*8+i][wid*32+nt2*16+l16]
    bf16x8 bfrag[2][4];
    float bgv[2] = {0.f, 0.f};
    #pragma unroll
    for (int nt2=0; nt2<2; nt2++) {
        const int col = wid*32 + nt2*16 + l16;
        #pragma unroll
        for (int ks=0; ks<4; ks++) {
            ushort tmp[8];
            #pragma unroll
            for (int i=0; i<8; i++)
                tmp[i] = f2bf(W[(size_t)(ks*32 + lk*8 + i)*CZ + col]);
            bfrag[nt2][ks] = *(const bf16x8*)tmp;
        }
        if (m == 3) bgv[nt2] = bg[col];
    }

    #pragma unroll 1
    for (int rt=0; rt<8; rt++) {
        const int row0 = rblk*128 + rt*16;
        bf16x8 af[4];
        #pragma unroll
        for (int ks=0; ks<4; ks++)
            af[ks] = *(const bf16x8*)(zl + (size_t)(row0 + l16)*CZ + ks*32 + lk*8);
        #pragma unroll
        for (int nt2=0; nt2<2; nt2++) {
            f32x4 acc = {0.f,0.f,0.f,0.f};
            #pragma unroll
            for (int ks=0; ks<4; ks++)
                acc = __builtin_amdgcn_mfma_f32_16x16x32_bf16(af[ks], bfrag[nt2][ks], acc, 0, 0, 0);
            const int ocol = wid*32 + nt2*16 + l16;
            const int orow = row0 + lk*4;
            if (m == 3) {
                #pragma unroll
                for (int rr=0; rr<4; rr++) {
                    const float val = 1.f/(1.f + __expf(-(acc[rr] + bgv[nt2])));
                    O[(size_t)(orow+rr)*CZ + ocol] = f2bf(val);
                }
            } else {
                #pragma unroll
                for (int rr=0; rr<4; rr++)
                    O[(size_t)(orow+rr)*CZ + ocol] = f2bf(acc[rr]);
            }
        }
    }
}

// ---------------- K3: windowed attention + gate (og aliases q), bf16 I/O ----------------
__global__ __launch_bounds__(256, 3) void k_attn(
    const ushort* __restrict__ q, const ushort* __restrict__ k, const ushort* __restrict__ v,
    const ushort* __restrict__ g, const float* __restrict__ tb, const float* __restrict__ mask,
    ushort* __restrict__ og)
{
    __shared__ float kl[47][NH][33];
    __shared__ float vl[47][NH][33];
    __shared__ float ml[47];
    const int i   = blockIdx.y;
    const int j0  = blockIdx.x * 32;
    const int tid = threadIdx.x;

    for (int idx = tid; idx < 47*16; idx += 256) {
        const int row = idx >> 4, c8 = idx & 15;
        const int jj  = j0 - 8 + row;
        const int jjc = min(max(jj, 0), N-1);
        const size_t goff = ((size_t)i*N + jjc)*CZ + c8*8;
        uint4 ku = *(const uint4*)(k + goff);
        uint4 vu = *(const uint4*)(v + goff);
        const int hh = c8 >> 2, co = (c8 & 3)*8;
        const ushort* ks_ = (const ushort*)&ku;
        const ushort* vs_ = (const ushort*)&vu;
        #pragma unroll
        for (int t=0; t<8; t++) {
            kl[row][hh][co+t] = bf2f(ks_[t]);
            vl[row][hh][co+t] = bf2f(vs_[t]);
        }
    }
    if (tid < 47) {
        const int jj  = j0 - 8 + tid;
        const int jjc = min(max(jj, 0), N-1);
        const bool ok = (jj >= 0) && (jj < N) && (mask[(size_t)i*N + jjc] > 0.f);
        ml[tid] = ok ? 0.f : -1e9f;
    }
    __syncthreads();

    const int chalf = tid & 1;
    const int h     = (tid >> 1) & 3;
    const int jloc  = tid >> 3;
    const int j     = j0 + jloc;
    const int c0l   = chalf * 16;
    const size_t base = ((size_t)i*N + j)*CZ + h*CH + c0l;

    float qv[16];
    {
        uint4 q1 = *(const uint4*)(q + base);
        uint4 q2 = *(const uint4*)(q + base + 8);
        const ushort* s1 = (const ushort*)&q1;
        const ushort* s2 = (const ushort*)&q2;
        #pragma unroll
        for (int t=0; t<8; t++) { qv[t] = bf2f(s1[t]); qv[8+t] = bf2f(s2[t]); }
    }

    const float scale = 0.17677669529663688f; // 1/sqrt(32)
    float lg[WIN];
    #pragma unroll
    for (int w=0; w<WIN; w++) {
        const int rel = jloc + w;
        float dot = 0.f;
        #pragma unroll
        for (int c4=0; c4<4; c4++) {
            float4 kv = *(const float4*)&kl[rel][h][c0l + c4*4];
            dot += qv[c4*4+0]*kv.x + qv[c4*4+1]*kv.y + qv[c4*4+2]*kv.z + qv[c4*4+3]*kv.w;
        }
        dot += __shfl_xor(dot, 1);
        const int jj  = j - 8 + w;
        const int jjc = min(max(jj, 0), N-1);
        lg[w] = dot*scale + tb[((size_t)j*N + jjc)*4 + h] + ml[rel];
    }
    float mx = lg[0];
    #pragma unroll
    for (int w=1; w<WIN; w++) mx = fmaxf(mx, lg[w]);
    float sum = 0.f;
    #pragma unroll
    for (int w=0; w<WIN; w++) { lg[w] = __expf(lg[w]-mx); sum += lg[w]; }
    const float inv = 1.f/sum;

    float o[16];
    #pragma unroll
    for (int c=0; c<16; c++) o[c] = 0.f;
    #pragma unroll
    for (int w=0; w<WIN; w++) {
        const float p   = lg[w]*inv;
        const int   rel = jloc + w;
        #pragma unroll
        for (int c4=0; c4<4; c4++) {
            float4 vv = *(const float4*)&vl[rel][h][c0l + c4*4];
            o[c4*4+0] += p*vv.x; o[c4*4+1] += p*vv.y;
            o[c4*4+2] += p*vv.z; o[c4*4+3] += p*vv.w;
        }
    }

    {
        uint4 g1 = *(const uint4*)(g + base);
        uint4 g2 = *(const uint4*)(g + base + 8);
        const ushort* s1 = (const ushort*)&g1;
        const ushort* s2 = (const ushort*)&g2;
        uint4 o1, o2; ushort* p1 = (ushort*)&o1; ushort* p2 = (ushort*)&o2;
        #pragma unroll
        for (int t=0; t<8; t++) {
            p1[t] = f2bf(o[t]   * bf2f(s1[t]));
            p2[t] = f2bf(o[8+t] * bf2f(s2[t]));
        }
        *(uint4*)(og + base)     = o1;   // og aliases q: read earlier by this thread only
        *(uint4*)(og + base + 8) = o2;
    }
}

// ---------------- K4: out = og @ w_out + b_out (MFMA, B in registers, fp32 out) ----------------
__global__ __launch_bounds__(256, 4) void k_outg(
    const ushort* __restrict__ og, const float* __restrict__ wout,
    const float* __restrict__ bout, float* __restrict__ out)
{
    const int rblk = blockIdx.x;
    const int tid = threadIdx.x;
    const int wid = tid >> 6, lane = tid & 63;
    const int l16 = lane & 15, lk = lane >> 4;

    bf16x8 bfrag[2][4];
    float bv[2];
    #pragma unroll
    for (int nt2=0; nt2<2; nt2++) {
        const int col = wid*32 + nt2*16 + l16;
        #pragma unroll
        for (int ks=0; ks<4; ks++) {
            ushort tmp[8];
            #pragma unroll
            for (int i=0; i<8; i++)
                tmp[i] = f2bf(wout[(size_t)(ks*32 + lk*8 + i)*CZ + col]);
            bfrag[nt2][ks] = *(const bf16x8*)tmp;
        }
        bv[nt2] = bout[col];
    }

    #pragma unroll 1
    for (int rt=0; rt<8; rt++) {
        const int row0 = rblk*128 + rt*16;
        bf16x8 af[4];
        #pragma unroll
        for (int ks=0; ks<4; ks++)
            af[ks] = *(const bf16x8*)(og + (size_t)(row0 + l16)*CZ + ks*32 + lk*8);
        #pragma unroll
        for (int nt2=0; nt2<2; nt2++) {
            f32x4 acc = {0.f,0.f,0.f,0.f};
            #pragma unroll
            for (int ks=0; ks<4; ks++)
                acc = __builtin_amdgcn_mfma_f32_16x16x32_bf16(af[ks], bfrag[nt2][ks], acc, 0, 0, 0);
            const int ocol = wid*32 + nt2*16 + l16;
            const int orow = row0 + lk*4;
            #pragma unroll
            for (int rr=0; rr<4; rr++)
                out[(size_t)(orow+rr)*CZ + ocol] = acc[rr] + bv[nt2];
        }
    }
}

extern "C" void kernel_launch(void* const* d_in, const int* in_sizes, int n_in,
                              void* d_out, int out_size, void* d_ws, size_t ws_size,
                              hipStream_t stream)
{
    const float* z    = (const float*)d_in[0];
    const float* mask = (const float*)d_in[1];
    const float* lnw  = (const float*)d_in[2];
    const float* lnb  = (const float*)d_in[3];
    const float* wq   = (const float*)d_in[4];
    const float* wk   = (const float*)d_in[5];
    const float* wv   = (const float*)d_in[6];
    const float* wb   = (const float*)d_in[7];
    const float* wg   = (const float*)d_in[8];
    const float* bg   = (const float*)d_in[9];
    const float* wo   = (const float*)d_in[10];
    const float* bo   = (const float*)d_in[11];

    const size_t NE = (size_t)NROWS*CZ;
    ushort* zl = (ushort*)d_ws;          // bf16 [NROWS][128]
    ushort* q  = zl + NE;
    ushort* k  = q + NE;
    ushort* v  = k + NE;
    ushort* g  = v + NE;
    float*  tb = (float*)(g + NE);       // f32 [NROWS][4]
    ushort* og = q;                      // alias (safe: per-thread read-then-write)
    if (ws_size < 5*NE*sizeof(ushort) + (size_t)NROWS*4*sizeof(float)) return;

    k_ln  <<<NROWS/16, 256, 0, stream>>>(z, lnw, lnb, wb, zl, tb);
    k_gemm<<<4*(NROWS/128), 256, 0, stream>>>(zl, wq, wk, wv, wg, bg, q, k, v, g);
    k_attn<<<dim3(N/32, N), 256, 0, stream>>>(q, k, v, g, tb, mask, og);
    k_outg<<<NROWS/128, 256, 0, stream>>>(og, wo, bo, (float*)d_out);
}

// Round 11
// 67.701 us; speedup vs baseline: 2.8729x; 1.1559x over previous
//
#include <hip/hip_runtime.h>
#include <hip/hip_bf16.h>

#define N 192
#define CZ 128
#define NH 4
#define CH 32
#define WIN 16
#define NROWS (N*N)   // 36864

typedef __attribute__((ext_vector_type(8))) short bf16x8;
typedef __attribute__((ext_vector_type(4))) float f32x4;

static __device__ __forceinline__ ushort f2bf(float x){
    union{float f; unsigned u;} a; a.f = x;
    unsigned r = a.u + 0x7fffu + ((a.u>>16)&1u);   // RNE
    return (ushort)(r>>16);
}
static __device__ __forceinline__ float bf2f(ushort s){
    union{unsigned u; float f;} a; a.u = ((unsigned)s)<<16;
    return a.f;
}

// ---------------- K1: LN (-> LDS) + q/k/v/g MFMA projections + tb ----------------
// Block = 128 rows, 4 waves. zl lives only in LDS. B-frags in registers.
// MFMA args swapped -> C^T layout: lane owns 1 row x 4 consecutive cols;
// per-wave LDS repack turns stores into full 64B sectors.
__global__ __launch_bounds__(256, 4) void k_proj(
    const float* __restrict__ z, const float* __restrict__ lnw, const float* __restrict__ lnb,
    const float* __restrict__ wbias,
    const float* __restrict__ wq, const float* __restrict__ wk,
    const float* __restrict__ wv, const float* __restrict__ wg,
    const float* __restrict__ bg,
    ushort* __restrict__ q, ushort* __restrict__ k,
    ushort* __restrict__ v, ushort* __restrict__ g, float* __restrict__ tb)
{
    __shared__ ushort zlds[128][132];   // +4 pad: 264B row stride -> even LDS banks
    __shared__ ushort st[4][16][36];    // per-wave store-repack scratch
    const int rbase = blockIdx.x * 128;
    const int tid  = threadIdx.x;
    const int wid  = tid >> 6, lane = tid & 63;
    const int l16  = lane & 15, lk = lane >> 4;

    // ---- LN phase: 8 x 16 rows ----
    for (int it = 0; it < 8; ++it) {
        const int r  = it*16 + wid*4 + lk;
        const float* zr = z + (size_t)(rbase + r)*CZ + l16*8;
        float4 a = ((const float4*)zr)[0];
        float4 b = ((const float4*)zr)[1];
        float s  = a.x+a.y+a.z+a.w + b.x+b.y+b.z+b.w;
        float s2 = a.x*a.x+a.y*a.y+a.z*a.z+a.w*a.w + b.x*b.x+b.y*b.y+b.z*b.z+b.w*b.w;
        #pragma unroll
        for (int off=1; off<16; off<<=1) { s += __shfl_xor(s, off); s2 += __shfl_xor(s2, off); }
        const float mu   = s * (1.f/CZ);
        const float rstd = rsqrtf(s2*(1.f/CZ) - mu*mu + 1e-5f);
        const int c0 = l16*8;
        float vals[8] = {a.x,a.y,a.z,a.w,b.x,b.y,b.z,b.w};
        float tbp[4] = {0.f,0.f,0.f,0.f};
        uint4 pk; ushort* ph = (ushort*)&pk;
        #pragma unroll
        for (int t=0; t<8; t++) {
            const float nv = (vals[t]-mu)*rstd*lnw[c0+t] + lnb[c0+t];
            ph[t] = f2bf(nv);
            float4 wb4 = *(const float4*)(wbias + (c0+t)*4);
            tbp[0] += nv*wb4.x; tbp[1] += nv*wb4.y;
            tbp[2] += nv*wb4.z; tbp[3] += nv*wb4.w;
        }
        *(uint4*)&zlds[r][c0] = pk;
        #pragma unroll
        for (int off=1; off<16; off<<=1) {
            #pragma unroll
            for (int h=0; h<4; h++) tbp[h] += __shfl_xor(tbp[h], off);
        }
        if (l16 == 0) *(float4*)(tb + (size_t)(rbase+r)*4) = make_float4(tbp[0],tbp[1],tbp[2],tbp[3]);
    }
    __syncthreads();

    // ---- projection phase: 4 matrices, wave owns cols [wid*32, wid*32+32) ----
    for (int m = 0; m < 4; ++m) {
        const float* W = (m==0)?wq:(m==1)?wk:(m==2)?wv:wg;
        ushort*      O = (m==0)?q :(m==1)?k :(m==2)?v :g;

        bf16x8 bfrag[2][4];
        float4 bg4[2];
        #pragma unroll
        for (int nt2=0; nt2<2; nt2++) {
            const int col = wid*32 + nt2*16 + l16;
            #pragma unroll
            for (int ks=0; ks<4; ks++) {
                ushort tmp[8];
                #pragma unroll
                for (int i=0; i<8; i++)
                    tmp[i] = f2bf(W[(size_t)(ks*32 + lk*8 + i)*CZ + col]);
                bfrag[nt2][ks] = *(const bf16x8*)tmp;
            }
            if (m == 3) bg4[nt2] = *(const float4*)(bg + wid*32 + nt2*16 + lk*4);
        }

        #pragma unroll 1
        for (int rt=0; rt<8; rt++) {
            bf16x8 af[4];
            #pragma unroll
            for (int ks=0; ks<4; ks++)
                af[ks] = *(const bf16x8*)&zlds[rt*16 + l16][ks*32 + lk*8];
            #pragma unroll
            for (int nt2=0; nt2<2; nt2++) {
                f32x4 acc = {0.f,0.f,0.f,0.f};
                #pragma unroll
                for (int ks=0; ks<4; ks++)   // swapped args -> C^T fragment layout
                    acc = __builtin_amdgcn_mfma_f32_16x16x32_bf16(bfrag[nt2][ks], af[ks], acc, 0, 0, 0);
                // thread holds row (rt*16+l16), cols wid*32+nt2*16+lk*4 .. +3
                float v0,v1,v2,v3;
                if (m == 3) {
                    v0 = 1.f/(1.f + __expf(-(acc[0] + bg4[nt2].x)));
                    v1 = 1.f/(1.f + __expf(-(acc[1] + bg4[nt2].y)));
                    v2 = 1.f/(1.f + __expf(-(acc[2] + bg4[nt2].z)));
                    v3 = 1.f/(1.f + __expf(-(acc[3] + bg4[nt2].w)));
                } else { v0=acc[0]; v1=acc[1]; v2=acc[2]; v3=acc[3]; }
                uint2 pk2;
                pk2.x = (unsigned)f2bf(v0) | ((unsigned)f2bf(v1)<<16);
                pk2.y = (unsigned)f2bf(v2) | ((unsigned)f2bf(v3)<<16);
                *(uint2*)&st[wid][l16][nt2*16 + lk*4] = pk2;
            }
            // readback: 4 lanes x 16B = full 64B sector per row
            const int row = lane >> 2, c8 = lane & 3;
            uint4 ov = *(const uint4*)&st[wid][row][c8*8];
            *(uint4*)(O + (size_t)(rbase + rt*16 + row)*CZ + wid*32 + c8*8) = ov;
        }
    }
}

// ---------------- K2: windowed attention + gate + out-GEMM fused ----------------
__global__ __launch_bounds__(256, 3) void k_attn_out(
    const ushort* __restrict__ q, const ushort* __restrict__ k, const ushort* __restrict__ v,
    const ushort* __restrict__ g, const float* __restrict__ tb, const float* __restrict__ mask,
    const float* __restrict__ wout, const float* __restrict__ bout, float* __restrict__ out)
{
    __shared__ float kl[47][NH][33];
    __shared__ float vl[47][NH][33];
    __shared__ float ml[47];
    ushort (*po)[132] = (ushort (*)[132])&kl[0][0][0];   // aliases kl after barrier

    const int i   = blockIdx.y;
    const int j0  = blockIdx.x * 32;
    const int tid = threadIdx.x;

    for (int idx = tid; idx < 47*16; idx += 256) {
        const int row = idx >> 4, c8 = idx & 15;
        const int jj  = j0 - 8 + row;
        const int jjc = min(max(jj, 0), N-1);
        const size_t goff = ((size_t)i*N + jjc)*CZ + c8*8;
        uint4 ku = *(const uint4*)(k + goff);
        uint4 vu = *(const uint4*)(v + goff);
        const int hh = c8 >> 2, co = (c8 & 3)*8;
        const ushort* ks_ = (const ushort*)&ku;
        const ushort* vs_ = (const ushort*)&vu;
        #pragma unroll
        for (int t=0; t<8; t++) {
            kl[row][hh][co+t] = bf2f(ks_[t]);
            vl[row][hh][co+t] = bf2f(vs_[t]);
        }
    }
    if (tid < 47) {
        const int jj  = j0 - 8 + tid;
        const int jjc = min(max(jj, 0), N-1);
        const bool ok = (jj >= 0) && (jj < N) && (mask[(size_t)i*N + jjc] > 0.f);
        ml[tid] = ok ? 0.f : -1e9f;
    }
    __syncthreads();

    const int chalf = tid & 1;
    const int h     = (tid >> 1) & 3;
    const int jloc  = tid >> 3;
    const int j     = j0 + jloc;
    const int c0l   = chalf * 16;
    const size_t base = ((size_t)i*N + j)*CZ + h*CH + c0l;

    float qv[16];
    {
        uint4 q1 = *(const uint4*)(q + base);
        uint4 q2 = *(const uint4*)(q + base + 8);
        const ushort* s1 = (const ushort*)&q1;
        const ushort* s2 = (const ushort*)&q2;
        #pragma unroll
        for (int t=0; t<8; t++) { qv[t] = bf2f(s1[t]); qv[8+t] = bf2f(s2[t]); }
    }

    const float scale = 0.17677669529663688f; // 1/sqrt(32)
    float lg[WIN];
    #pragma unroll
    for (int w=0; w<WIN; w++) {
        const int rel = jloc + w;
        float dot = 0.f;
        #pragma unroll
        for (int c4=0; c4<4; c4++) {
            float4 kv = *(const float4*)&kl[rel][h][c0l + c4*4];
            dot += qv[c4*4+0]*kv.x + qv[c4*4+1]*kv.y + qv[c4*4+2]*kv.z + qv[c4*4+3]*kv.w;
        }
        dot += __shfl_xor(dot, 1);
        const int jj  = j - 8 + w;
        const int jjc = min(max(jj, 0), N-1);
        lg[w] = dot*scale + tb[((size_t)j*N + jjc)*4 + h] + ml[rel];
    }
    float mx = lg[0];
    #pragma unroll
    for (int w=1; w<WIN; w++) mx = fmaxf(mx, lg[w]);
    float sum = 0.f;
    #pragma unroll
    for (int w=0; w<WIN; w++) { lg[w] = __expf(lg[w]-mx); sum += lg[w]; }
    const float inv = 1.f/sum;

    float o[16];
    #pragma unroll
    for (int c=0; c<16; c++) o[c] = 0.f;
    #pragma unroll
    for (int w=0; w<WIN; w++) {
        const float p   = lg[w]*inv;
        const int   rel = jloc + w;
        #pragma unroll
        for (int c4=0; c4<4; c4++) {
            float4 vv = *(const float4*)&vl[rel][h][c0l + c4*4];
            o[c4*4+0] += p*vv.x; o[c4*4+1] += p*vv.y;
            o[c4*4+2] += p*vv.z; o[c4*4+3] += p*vv.w;
        }
    }

    uint4 o1, o2;
    {
        uint4 g1 = *(const uint4*)(g + base);
        uint4 g2 = *(const uint4*)(g + base + 8);
        const ushort* s1 = (const ushort*)&g1;
        const ushort* s2 = (const ushort*)&g2;
        ushort* p1 = (ushort*)&o1; ushort* p2 = (ushort*)&o2;
        #pragma unroll
        for (int t=0; t<8; t++) {
            p1[t] = f2bf(o[t]   * bf2f(s1[t]));
            p2[t] = f2bf(o[8+t] * bf2f(s2[t]));
        }
    }
    __syncthreads();                 // all kl/vl reads done -> safe to overwrite with po
    *(uint4*)&po[jloc][h*CH + c0l]     = o1;
    *(uint4*)&po[jloc][h*CH + c0l + 8] = o2;

    // ---- out-GEMM: wave owns cols [wid*32, wid*32+32) ----
    const int wid = tid >> 6, lane = tid & 63;
    const int l16 = lane & 15, lk = lane >> 4;
    bf16x8 bfrag[2][4];
    float4 bo4[2];
    #pragma unroll
    for (int nt2=0; nt2<2; nt2++) {
        const int col = wid*32 + nt2*16 + l16;
        #pragma unroll
        for (int ks=0; ks<4; ks++) {
            ushort tmp[8];
            #pragma unroll
            for (int t=0; t<8; t++)
                tmp[t] = f2bf(wout[(size_t)(ks*32 + lk*8 + t)*CZ + col]);
            bfrag[nt2][ks] = *(const bf16x8*)tmp;
        }
        bo4[nt2] = *(const float4*)(bout + wid*32 + nt2*16 + lk*4);
    }
    __syncthreads();

    #pragma unroll
    for (int rt=0; rt<2; rt++) {
        bf16x8 af[4];
        #pragma unroll
        for (int ks=0; ks<4; ks++)
            af[ks] = *(const bf16x8*)&po[rt*16 + l16][ks*32 + lk*8];
        const size_t orow = (size_t)(i*N + j0 + rt*16 + l16)*CZ;
        #pragma unroll
        for (int nt2=0; nt2<2; nt2++) {
            f32x4 acc = {0.f,0.f,0.f,0.f};
            #pragma unroll
            for (int ks=0; ks<4; ks++)   // swapped -> C^T: row=l16, 4 consecutive cols
                acc = __builtin_amdgcn_mfma_f32_16x16x32_bf16(bfrag[nt2][ks], af[ks], acc, 0, 0, 0);
            float4 ov;
            ov.x = acc[0] + bo4[nt2].x; ov.y = acc[1] + bo4[nt2].y;
            ov.z = acc[2] + bo4[nt2].z; ov.w = acc[3] + bo4[nt2].w;
            *(float4*)(out + orow + wid*32 + nt2*16 + lk*4) = ov;
        }
    }
}

extern "C" void kernel_launch(void* const* d_in, const int* in_sizes, int n_in,
                              void* d_out, int out_size, void* d_ws, size_t ws_size,
                              hipStream_t stream)
{
    const float* z    = (const float*)d_in[0];
    const float* mask = (const float*)d_in[1];
    const float* lnw  = (const float*)d_in[2];
    const float* lnb  = (const float*)d_in[3];
    const float* wq   = (const float*)d_in[4];
    const float* wk   = (const float*)d_in[5];
    const float* wv   = (const float*)d_in[6];
    const float* wb   = (const float*)d_in[7];
    const float* wg   = (const float*)d_in[8];
    const float* bg   = (const float*)d_in[9];
    const float* wo   = (const float*)d_in[10];
    const float* bo   = (const float*)d_in[11];

    const size_t NE = (size_t)NROWS*CZ;
    ushort* q  = (ushort*)d_ws;
    ushort* k  = q + NE;
    ushort* v  = k + NE;
    ushort* g  = v + NE;
    float*  tb = (float*)(g + NE);       // f32 [NROWS][4]
    if (ws_size < 4*NE*sizeof(ushort) + (size_t)NROWS*4*sizeof(float)) return;

    k_proj<<<NROWS/128, 256, 0, stream>>>(z, lnw, lnb, wb, wq, wk, wv, wg, bg, q, k, v, g, tb);
    k_attn_out<<<dim3(N/32, N), 256, 0, stream>>>(q, k, v, g, tb, mask, wo, bo, (float*)d_out);
}